// Round 2
// baseline (235.951 us; speedup 1.0000x reference)
//
#include <hip/hip_runtime.h>
#include <hip/hip_bf16.h>
#include <stdint.h>

#define OUTF 4096
#define INF  4096
#define MROWS 4096
#define GS 32

typedef __attribute__((ext_vector_type(8))) __bf16 bf16x8;
typedef __attribute__((ext_vector_type(4))) float f32x4;

// ---------------- prepass: fp32 x -> bf16 ----------------
__global__ void cvt_x_kernel(const float* __restrict__ x, __bf16* __restrict__ xb, int n8) {
    int i = blockIdx.x * blockDim.x + threadIdx.x;
    if (i >= n8) return;
    const f32x4* xp = (const f32x4*)x;
    f32x4 a = xp[2 * i], b = xp[2 * i + 1];
    bf16x8 v = { (__bf16)a[0], (__bf16)a[1], (__bf16)a[2], (__bf16)a[3],
                 (__bf16)b[0], (__bf16)b[1], (__bf16)b[2], (__bf16)b[3] };
    ((bf16x8*)xb)[i] = v;
}

// Gather the 12 packed bytes of group `gid` from the int32-expanded device
// buffer (harness stores integer inputs as sign-extended int32).
__device__ inline void load_group_bits(const int* __restrict__ wq, int gid,
                                       uint64_t& lo, uint64_t& hi) {
    const int4* p = (const int4*)(wq + (size_t)gid * 12);  // 48B, 16B-aligned
    int4 A = p[0], B = p[1], C = p[2];
    uint32_t d0 = (uint32_t)(A.x & 255) | ((uint32_t)(A.y & 255) << 8) |
                  ((uint32_t)(A.z & 255) << 16) | ((uint32_t)(A.w & 255) << 24);
    uint32_t d1 = (uint32_t)(B.x & 255) | ((uint32_t)(B.y & 255) << 8) |
                  ((uint32_t)(B.z & 255) << 16) | ((uint32_t)(B.w & 255) << 24);
    uint32_t d2 = (uint32_t)(C.x & 255) | ((uint32_t)(C.y & 255) << 8) |
                  ((uint32_t)(C.z & 255) << 16) | ((uint32_t)(C.w & 255) << 24);
    lo = (uint64_t)d0 | ((uint64_t)d1 << 32);
    hi = (uint64_t)d1 | ((uint64_t)d2 << 32);
}

// ---------------- prepass: 3-bit packed W -> bf16 [OUT][IN] ----------------
__global__ void dequant_w_kernel(const int* __restrict__ wq,
                                 const float* __restrict__ wn,
                                 __bf16* __restrict__ wb) {
    int gid = blockIdx.x * blockDim.x + threadIdx.x; // one 32-elem group per thread
    uint64_t lo, hi;
    load_group_bits(wq, gid, lo, hi);
    float nrm = wn[gid];
    float c2 = nrm * (2.0f / 7.0f), c1 = -nrm;  // w = q*(2n/7) - n
    bf16x8 o[4];
#pragma unroll
    for (int j = 0; j < 32; ++j) {
        uint32_t q = (j <= 20) ? (uint32_t)((lo >> (3 * j)) & 7)
                               : (uint32_t)((hi >> (3 * j - 32)) & 7);
        o[j >> 3][j & 7] = (__bf16)((float)q * c2 + c1);
    }
    bf16x8* outp = (bf16x8*)(wb + (size_t)gid * 32);
    outp[0] = o[0]; outp[1] = o[1]; outp[2] = o[2]; outp[3] = o[3];
}

// ---------------- GEMM: C = X * W^T + bias ----------------
// 128x128 tile, BK=64, 256 threads (4 waves, 2x2), mfma_f32_16x16x32_bf16.
// LDS tiles [128 rows][64 bf16] with byte-XOR swizzle: col ^ ((row&7)<<4).
template <bool PRE>
__global__ __launch_bounds__(256, 2) void gemm_kernel(
    const float* __restrict__ x, const __bf16* __restrict__ xb,
    const int* __restrict__ wq, const float* __restrict__ wn,
    const __bf16* __restrict__ wb, const float* __restrict__ bias,
    float* __restrict__ out) {
    __shared__ __align__(16) unsigned char lAraw[128 * 128];
    __shared__ __align__(16) unsigned char lBraw[128 * 128];

    const int tid = threadIdx.x;
    const int lane = tid & 63, wid = tid >> 6;
    const int wr = wid >> 1, wc = wid & 1;
    const int bn = blockIdx.x, bm = blockIdx.y;
    const int row16 = lane & 15, kq = lane >> 4;

    f32x4 acc[4][4] = {};

    // LDS read offsets for kk=0 (kk=1 is ^64: bit 6 toggles under XOR-swizzle)
    int aoff[4], boff[4];
#pragma unroll
    for (int m = 0; m < 4; ++m) {
        int r = wr * 64 + m * 16 + row16;
        aoff[m] = r * 128 + ((kq * 16) ^ ((r & 7) << 4));
    }
#pragma unroll
    for (int n = 0; n < 4; ++n) {
        int r = wc * 64 + n * 16 + row16;
        boff[n] = r * 128 + ((kq * 16) ^ ((r & 7) << 4));
    }

    for (int kt = 0; kt < INF / 64; ++kt) {
        __syncthreads();
        if (PRE) {
#pragma unroll
            for (int it = 0; it < 4; ++it) {
                int chunk = it * 256 + tid;
                int row = chunk >> 3, c = chunk & 7;
                bf16x8 v = *(const bf16x8*)(xb + (size_t)(bm * 128 + row) * INF + kt * 64 + c * 8);
                *(bf16x8*)(lAraw + row * 128 + ((c * 16) ^ ((row & 7) << 4))) = v;
            }
#pragma unroll
            for (int it = 0; it < 4; ++it) {
                int chunk = it * 256 + tid;
                int row = chunk >> 3, c = chunk & 7;
                bf16x8 v = *(const bf16x8*)(wb + (size_t)(bn * 128 + row) * INF + kt * 64 + c * 8);
                *(bf16x8*)(lBraw + row * 128 + ((c * 16) ^ ((row & 7) << 4))) = v;
            }
        } else {
            // X: fp32 -> bf16 on the fly
#pragma unroll
            for (int it = 0; it < 4; ++it) {
                int row = it * 32 + (tid >> 3), c = tid & 7;
                const f32x4* xp = (const f32x4*)(x + (size_t)(bm * 128 + row) * INF + kt * 64 + c * 8);
                f32x4 a0 = xp[0], a1 = xp[1];
                bf16x8 v = { (__bf16)a0[0], (__bf16)a0[1], (__bf16)a0[2], (__bf16)a0[3],
                             (__bf16)a1[0], (__bf16)a1[1], (__bf16)a1[2], (__bf16)a1[3] };
                *(bf16x8*)(lAraw + row * 128 + ((c * 16) ^ ((row & 7) << 4))) = v;
            }
            // W: unpack one 3-bit group (32 elems) per thread
            int row = tid >> 1, gi = tid & 1;
            int gid = (bn * 128 + row) * (INF / GS) + kt * 2 + gi;
            uint64_t lo, hi;
            load_group_bits(wq, gid, lo, hi);
            float nrm = wn[gid];
            float c2 = nrm * (2.0f / 7.0f), c1 = -nrm;
            bf16x8 o[4];
#pragma unroll
            for (int j = 0; j < 32; ++j) {
                uint32_t q = (j <= 20) ? (uint32_t)((lo >> (3 * j)) & 7)
                                       : (uint32_t)((hi >> (3 * j - 32)) & 7);
                o[j >> 3][j & 7] = (__bf16)((float)q * c2 + c1);
            }
            unsigned swz = (row & 7) << 4;
#pragma unroll
            for (int c4 = 0; c4 < 4; ++c4)
                *(bf16x8*)(lBraw + row * 128 + ((gi * 64 + c4 * 16) ^ swz)) = o[c4];
        }
        __syncthreads();

#pragma unroll
        for (int kk = 0; kk < 2; ++kk) {
            bf16x8 af[4], bff[4];
#pragma unroll
            for (int m = 0; m < 4; ++m)
                af[m] = *(const bf16x8*)(lAraw + (aoff[m] ^ (kk * 64)));
#pragma unroll
            for (int n = 0; n < 4; ++n)
                bff[n] = *(const bf16x8*)(lBraw + (boff[n] ^ (kk * 64)));
#pragma unroll
            for (int m = 0; m < 4; ++m)
#pragma unroll
                for (int n = 0; n < 4; ++n)
                    acc[m][n] = __builtin_amdgcn_mfma_f32_16x16x32_bf16(af[m], bff[n], acc[m][n], 0, 0, 0);
        }
    }

    // epilogue: C = acc + bias
#pragma unroll
    for (int n = 0; n < 4; ++n) {
        int col = bn * 128 + wc * 64 + n * 16 + row16;
        float bv = bias[col];
#pragma unroll
        for (int m = 0; m < 4; ++m) {
            int rbase = bm * 128 + wr * 64 + m * 16 + kq * 4;
#pragma unroll
            for (int j = 0; j < 4; ++j)
                out[(size_t)(rbase + j) * OUTF + col] = acc[m][n][j] + bv;
        }
    }
}

extern "C" void kernel_launch(void* const* d_in, const int* in_sizes, int n_in,
                              void* d_out, int out_size, void* d_ws, size_t ws_size,
                              hipStream_t stream) {
    const float* x    = (const float*)d_in[0];
    const int*   wq   = (const int*)d_in[1];
    const float* wn   = (const float*)d_in[2];
    const float* bias = (const float*)d_in[3];
    float* out = (float*)d_out;

    const size_t xb_bytes = (size_t)MROWS * INF * 2;  // 32 MB
    const size_t wb_bytes = (size_t)OUTF * INF * 2;   // 32 MB
    if (ws_size >= xb_bytes + wb_bytes) {
        __bf16* xb = (__bf16*)d_ws;
        __bf16* wb = (__bf16*)((char*)d_ws + xb_bytes);
        cvt_x_kernel<<<(MROWS * INF / 8 + 255) / 256, 256, 0, stream>>>(x, xb, MROWS * INF / 8);
        dequant_w_kernel<<<(OUTF * INF / GS) / 256, 256, 0, stream>>>(wq, wn, wb);
        gemm_kernel<true><<<dim3(OUTF / 128, MROWS / 128), 256, 0, stream>>>(
            x, xb, wq, wn, wb, bias, out);
    } else {
        gemm_kernel<false><<<dim3(OUTF / 128, MROWS / 128), 256, 0, stream>>>(
            x, nullptr, wq, wn, nullptr, bias, out);
    }
}

// Round 3
// 160.895 us; speedup vs baseline: 1.4665x; 1.4665x over previous
//
#include <hip/hip_runtime.h>
#include <hip/hip_bf16.h>
#include <stdint.h>

#define OUTF 4096
#define INF  4096
#define MROWS 4096
#define GS 32

typedef __attribute__((ext_vector_type(8))) __bf16 bf16x8;
typedef __attribute__((ext_vector_type(4))) float f32x4;

__device__ inline void gload_lds16(const void* g, void* l) {
    __builtin_amdgcn_global_load_lds(
        (const __attribute__((address_space(1))) void*)g,
        (__attribute__((address_space(3))) void*)l, 16, 0, 0);
}

// ---------------- prepass: fp32 x -> bf16 ----------------
__global__ void cvt_x_kernel(const float* __restrict__ x, __bf16* __restrict__ xb, int n8) {
    int i = blockIdx.x * blockDim.x + threadIdx.x;
    if (i >= n8) return;
    const f32x4* xp = (const f32x4*)x;
    f32x4 a = xp[2 * i], b = xp[2 * i + 1];
    bf16x8 v = { (__bf16)a[0], (__bf16)a[1], (__bf16)a[2], (__bf16)a[3],
                 (__bf16)b[0], (__bf16)b[1], (__bf16)b[2], (__bf16)b[3] };
    ((bf16x8*)xb)[i] = v;
}

// Gather the 12 packed bytes of group `gid` from the int32-expanded device
// buffer (harness stores integer inputs as sign-extended int32).
__device__ inline void load_group_bits(const int* __restrict__ wq, int gid,
                                       uint64_t& lo, uint64_t& hi) {
    const int4* p = (const int4*)(wq + (size_t)gid * 12);  // 48B, 16B-aligned
    int4 A = p[0], B = p[1], C = p[2];
    uint32_t d0 = (uint32_t)(A.x & 255) | ((uint32_t)(A.y & 255) << 8) |
                  ((uint32_t)(A.z & 255) << 16) | ((uint32_t)(A.w & 255) << 24);
    uint32_t d1 = (uint32_t)(B.x & 255) | ((uint32_t)(B.y & 255) << 8) |
                  ((uint32_t)(B.z & 255) << 16) | ((uint32_t)(B.w & 255) << 24);
    uint32_t d2 = (uint32_t)(C.x & 255) | ((uint32_t)(C.y & 255) << 8) |
                  ((uint32_t)(C.z & 255) << 16) | ((uint32_t)(C.w & 255) << 24);
    lo = (uint64_t)d0 | ((uint64_t)d1 << 32);
    hi = (uint64_t)d1 | ((uint64_t)d2 << 32);
}

// ---------------- prepass: 3-bit packed W -> bf16 [OUT][IN] ----------------
__global__ void dequant_w_kernel(const int* __restrict__ wq,
                                 const float* __restrict__ wn,
                                 __bf16* __restrict__ wb) {
    int gid = blockIdx.x * blockDim.x + threadIdx.x; // one 32-elem group per thread
    uint64_t lo, hi;
    load_group_bits(wq, gid, lo, hi);
    float nrm = wn[gid];
    float c2 = nrm * (2.0f / 7.0f), c1 = -nrm;  // w = q*(2n/7) - n
    bf16x8 o[4];
#pragma unroll
    for (int j = 0; j < 32; ++j) {
        uint32_t q = (j <= 20) ? (uint32_t)((lo >> (3 * j)) & 7)
                               : (uint32_t)((hi >> (3 * j - 32)) & 7);
        o[j >> 3][j & 7] = (__bf16)((float)q * c2 + c1);
    }
    bf16x8* outp = (bf16x8*)(wb + (size_t)gid * 32);
    outp[0] = o[0]; outp[1] = o[1]; outp[2] = o[2]; outp[3] = o[3];
}

// ---------------- GEMM: C = X * W^T + bias ----------------
// 128x128 tile, BK=64, 256 threads (4 waves, 2x2), mfma_f32_16x16x32_bf16.
// LDS tiles [128 rows][64 bf16], XOR swizzle in 16B-chunk index: c ^= (row&7).
// PRE path: global_load_lds direct (linear LDS dest, pre-swizzled global src).
template <bool PRE>
__global__ __launch_bounds__(256, 2) void gemm_kernel(
    const float* __restrict__ x, const __bf16* __restrict__ xb,
    const int* __restrict__ wq, const float* __restrict__ wn,
    const __bf16* __restrict__ wb, const float* __restrict__ bias,
    float* __restrict__ out) {
    __shared__ __align__(16) unsigned char lAraw[128 * 128];
    __shared__ __align__(16) unsigned char lBraw[128 * 128];

    const int tid = threadIdx.x;
    const int lane = tid & 63, wid = tid >> 6;
    const int wr = wid >> 1, wc = wid & 1;
    const int bn = blockIdx.x, bm = blockIdx.y;
    const int row16 = lane & 15, kq = lane >> 4;

    f32x4 acc[4][4] = {};

    // LDS read offsets for kk=0 (kk=1 is ^64: bit 6 toggles under XOR-swizzle)
    int aoff[4], boff[4];
#pragma unroll
    for (int m = 0; m < 4; ++m) {
        int r = wr * 64 + m * 16 + row16;
        aoff[m] = r * 128 + ((kq * 16) ^ ((r & 7) << 4));
    }
#pragma unroll
    for (int n = 0; n < 4; ++n) {
        int r = wc * 64 + n * 16 + row16;
        boff[n] = r * 128 + ((kq * 16) ^ ((r & 7) << 4));
    }

    // Pre-swizzled global source geometry for gload_lds (PRE path):
    // segment seg (1KB) covers rows seg*8 .. seg*8+7; lane l writes LDS
    // linearly at seg*1024 + l*16 -> (row = seg*8 + (l>>3), chunk = l&7);
    // content there must be global chunk (l&7) ^ (row&7).
    const int srow = lane >> 3;
    const int schunk = (lane & 7) ^ (srow & 7);  // row&7 == srow&7 since seg*8 is 8-aligned

    for (int kt = 0; kt < INF / 64; ++kt) {
        __syncthreads();
        if (PRE) {
#pragma unroll
            for (int it = 0; it < 4; ++it) {
                int seg = wid * 4 + it;          // 0..15
                int row = seg * 8 + srow;
                const char* src = (const char*)xb +
                    ((size_t)(bm * 128 + row) * INF + kt * 64 + schunk * 8) * 2;
                gload_lds16(src, lAraw + seg * 1024);
            }
#pragma unroll
            for (int it = 0; it < 4; ++it) {
                int seg = wid * 4 + it;
                int row = seg * 8 + srow;
                const char* src = (const char*)wb +
                    ((size_t)(bn * 128 + row) * INF + kt * 64 + schunk * 8) * 2;
                gload_lds16(src, lBraw + seg * 1024);
            }
        } else {
            // X: fp32 -> bf16 on the fly
#pragma unroll
            for (int it = 0; it < 4; ++it) {
                int row = it * 32 + (tid >> 3), c = tid & 7;
                const f32x4* xp = (const f32x4*)(x + (size_t)(bm * 128 + row) * INF + kt * 64 + c * 8);
                f32x4 a0 = xp[0], a1 = xp[1];
                bf16x8 v = { (__bf16)a0[0], (__bf16)a0[1], (__bf16)a0[2], (__bf16)a0[3],
                             (__bf16)a1[0], (__bf16)a1[1], (__bf16)a1[2], (__bf16)a1[3] };
                *(bf16x8*)(lAraw + row * 128 + ((c * 16) ^ ((row & 7) << 4))) = v;
            }
            // W: unpack one 3-bit group (32 elems) per thread
            int row = tid >> 1, gi = tid & 1;
            int gid = (bn * 128 + row) * (INF / GS) + kt * 2 + gi;
            uint64_t lo, hi;
            load_group_bits(wq, gid, lo, hi);
            float nrm = wn[gid];
            float c2 = nrm * (2.0f / 7.0f), c1 = -nrm;
            bf16x8 o[4];
#pragma unroll
            for (int j = 0; j < 32; ++j) {
                uint32_t q = (j <= 20) ? (uint32_t)((lo >> (3 * j)) & 7)
                                       : (uint32_t)((hi >> (3 * j - 32)) & 7);
                o[j >> 3][j & 7] = (__bf16)((float)q * c2 + c1);
            }
            unsigned swz = (row & 7) << 4;
#pragma unroll
            for (int c4 = 0; c4 < 4; ++c4)
                *(bf16x8*)(lBraw + row * 128 + ((gi * 64 + c4 * 16) ^ swz)) = o[c4];
        }
        __syncthreads();

#pragma unroll
        for (int kk = 0; kk < 2; ++kk) {
            bf16x8 af[4], bff[4];
#pragma unroll
            for (int m = 0; m < 4; ++m)
                af[m] = *(const bf16x8*)(lAraw + (aoff[m] ^ (kk * 64)));
#pragma unroll
            for (int n = 0; n < 4; ++n)
                bff[n] = *(const bf16x8*)(lBraw + (boff[n] ^ (kk * 64)));
#pragma unroll
            for (int m = 0; m < 4; ++m)
#pragma unroll
                for (int n = 0; n < 4; ++n)
                    acc[m][n] = __builtin_amdgcn_mfma_f32_16x16x32_bf16(af[m], bff[n], acc[m][n], 0, 0, 0);
        }
    }

    // epilogue: C = acc + bias
#pragma unroll
    for (int n = 0; n < 4; ++n) {
        int col = bn * 128 + wc * 64 + n * 16 + row16;
        float bv = bias[col];
#pragma unroll
        for (int m = 0; m < 4; ++m) {
            int rbase = bm * 128 + wr * 64 + m * 16 + kq * 4;
#pragma unroll
            for (int j = 0; j < 4; ++j)
                out[(size_t)(rbase + j) * OUTF + col] = acc[m][n][j] + bv;
        }
    }
}

extern "C" void kernel_launch(void* const* d_in, const int* in_sizes, int n_in,
                              void* d_out, int out_size, void* d_ws, size_t ws_size,
                              hipStream_t stream) {
    const float* x    = (const float*)d_in[0];
    const int*   wq   = (const int*)d_in[1];
    const float* wn   = (const float*)d_in[2];
    const float* bias = (const float*)d_in[3];
    float* out = (float*)d_out;

    const size_t xb_bytes = (size_t)MROWS * INF * 2;  // 32 MB
    const size_t wb_bytes = (size_t)OUTF * INF * 2;   // 32 MB
    if (ws_size >= xb_bytes + wb_bytes) {
        __bf16* xb = (__bf16*)d_ws;
        __bf16* wb = (__bf16*)((char*)d_ws + xb_bytes);
        cvt_x_kernel<<<(MROWS * INF / 8 + 255) / 256, 256, 0, stream>>>(x, xb, MROWS * INF / 8);
        dequant_w_kernel<<<(OUTF * INF / GS) / 256, 256, 0, stream>>>(wq, wn, wb);
        gemm_kernel<true><<<dim3(OUTF / 128, MROWS / 128), 256, 0, stream>>>(
            x, xb, wq, wn, wb, bias, out);
    } else {
        gemm_kernel<false><<<dim3(OUTF / 128, MROWS / 128), 256, 0, stream>>>(
            x, nullptr, wq, wn, nullptr, bias, out);
    }
}

// Round 4
// 142.429 us; speedup vs baseline: 1.6566x; 1.1297x over previous
//
#include <hip/hip_runtime.h>
#include <hip/hip_bf16.h>
#include <stdint.h>

#define OUTF 4096
#define INF  4096
#define MROWS 4096
#define GS 32

typedef __attribute__((ext_vector_type(8))) __bf16 bf16x8;
typedef __attribute__((ext_vector_type(4))) float f32x4;

__device__ inline void gload_lds16(const void* g, void* l) {
    __builtin_amdgcn_global_load_lds(
        (const __attribute__((address_space(1))) void*)g,
        (__attribute__((address_space(3))) void*)l, 16, 0, 0);
}

// ---------------- prepass: fp32 x -> bf16 ----------------
__global__ void cvt_x_kernel(const float* __restrict__ x, __bf16* __restrict__ xb, int n8) {
    int i = blockIdx.x * blockDim.x + threadIdx.x;
    if (i >= n8) return;
    const f32x4* xp = (const f32x4*)x;
    f32x4 a = xp[2 * i], b = xp[2 * i + 1];
    bf16x8 v = { (__bf16)a[0], (__bf16)a[1], (__bf16)a[2], (__bf16)a[3],
                 (__bf16)b[0], (__bf16)b[1], (__bf16)b[2], (__bf16)b[3] };
    ((bf16x8*)xb)[i] = v;
}

// Gather the 12 packed bytes of group `gid` (harness stores int8 input as
// sign-extended int32, 4B per packed byte).
__device__ inline void load_group_bits(const int* __restrict__ wq, int gid,
                                       uint64_t& lo, uint64_t& hi) {
    const int4* p = (const int4*)(wq + (size_t)gid * 12);
    int4 A = p[0], B = p[1], C = p[2];
    uint32_t d0 = (uint32_t)(A.x & 255) | ((uint32_t)(A.y & 255) << 8) |
                  ((uint32_t)(A.z & 255) << 16) | ((uint32_t)(A.w & 255) << 24);
    uint32_t d1 = (uint32_t)(B.x & 255) | ((uint32_t)(B.y & 255) << 8) |
                  ((uint32_t)(B.z & 255) << 16) | ((uint32_t)(B.w & 255) << 24);
    uint32_t d2 = (uint32_t)(C.x & 255) | ((uint32_t)(C.y & 255) << 8) |
                  ((uint32_t)(C.z & 255) << 16) | ((uint32_t)(C.w & 255) << 24);
    lo = (uint64_t)d0 | ((uint64_t)d1 << 32);
    hi = (uint64_t)d1 | ((uint64_t)d2 << 32);
}

// ---------------- prepass: 3-bit packed W -> bf16 [OUT][IN] ----------------
__global__ void dequant_w_kernel(const int* __restrict__ wq,
                                 const float* __restrict__ wn,
                                 __bf16* __restrict__ wb) {
    int gid = blockIdx.x * blockDim.x + threadIdx.x;
    uint64_t lo, hi;
    load_group_bits(wq, gid, lo, hi);
    float nrm = wn[gid];
    float c2 = nrm * (2.0f / 7.0f), c1 = -nrm;  // w = q*(2n/7) - n
    bf16x8 o[4];
#pragma unroll
    for (int j = 0; j < 32; ++j) {
        uint32_t q = (j <= 20) ? (uint32_t)((lo >> (3 * j)) & 7)
                               : (uint32_t)((hi >> (3 * j - 32)) & 7);
        o[j >> 3][j & 7] = (__bf16)((float)q * c2 + c1);
    }
    bf16x8* outp = (bf16x8*)(wb + (size_t)gid * 32);
    outp[0] = o[0]; outp[1] = o[1]; outp[2] = o[2]; outp[3] = o[3];
}

// =================== 256x256 8-phase GEMM (T2+T3+T4+T5) ===================
// BM=BN=256, BK=64, 512 threads (8 waves, 2Mx4N). Per-wave output 128x64,
// interleaved: M rows = wr*64 + mh*128 + m*16, N cols = wc*32 + nh*128 + n*16.
// LDS 128KB: [buf][A|B][half][row 0..127][64 bf16], 16B-chunk XOR swizzle
// chunk ^= row&7 (linear gload_lds dest + pre-swizzled global source).
// Per K-tile: 4 phases, zigzag quadrants (0,0)(0,1)(1,1)(1,0); stage next
// tile's half-tiles a0,b0,a1,b1 one per phase; vmcnt(2)@P1, vmcnt(4)@P4.

#define VMCNT(N) asm volatile("s_waitcnt vmcnt(" #N ")" ::: "memory")
#define BARR() do { asm volatile("" ::: "memory"); __builtin_amdgcn_s_barrier(); \
                    asm volatile("" ::: "memory"); } while (0)

#define LOADA(RB, H) do { \
    _Pragma("unroll") \
    for (int m_ = 0; m_ < 4; ++m_) { \
        const int r_ = wr * 64 + m_ * 16 + row16; \
        _Pragma("unroll") \
        for (int kk_ = 0; kk_ < 2; ++kk_) \
            af[m_][kk_] = *(const bf16x8*)(lds + (RB) * 65536 + (H) * 16384 + \
                r_ * 128 + (((kk_ * 4 + kq) * 16) ^ ((r_ & 7) << 4))); \
    } \
} while (0)

#define LOADB(RB, H) do { \
    _Pragma("unroll") \
    for (int n_ = 0; n_ < 2; ++n_) { \
        const int r_ = wc * 32 + n_ * 16 + row16; \
        _Pragma("unroll") \
        for (int kk_ = 0; kk_ < 2; ++kk_) \
            bf[n_][kk_] = *(const bf16x8*)(lds + (RB) * 65536 + 32768 + (H) * 16384 + \
                r_ * 128 + (((kk_ * 4 + kq) * 16) ^ ((r_ & 7) << 4))); \
    } \
} while (0)

#define STAGEA(SB, H, SKT) do { \
    _Pragma("unroll") \
    for (int j_ = 0; j_ < 2; ++j_) \
        gload_lds16((const char*)(xb + (size_t)(bm * 256 + (H) * 128 + j_ * 64 + srow) * INF + \
                                  (SKT) * 64 + schunk * 8), \
                    lds + (SB) * 65536 + (H) * 16384 + j_ * 8192 + tid * 16); \
} while (0)

#define STAGEB(SB, H, SKT) do { \
    _Pragma("unroll") \
    for (int j_ = 0; j_ < 2; ++j_) \
        gload_lds16((const char*)(wb + (size_t)(bn * 256 + (H) * 128 + j_ * 64 + srow) * INF + \
                                  (SKT) * 64 + schunk * 8), \
                    lds + (SB) * 65536 + 32768 + (H) * 16384 + j_ * 8192 + tid * 16); \
} while (0)

#define MFMA16(MH, NH) do { \
    __builtin_amdgcn_s_setprio(1); \
    _Pragma("unroll") \
    for (int kk_ = 0; kk_ < 2; ++kk_) \
        _Pragma("unroll") \
        for (int m_ = 0; m_ < 4; ++m_) \
            _Pragma("unroll") \
            for (int n_ = 0; n_ < 2; ++n_) \
                acc[MH][NH][m_][n_] = __builtin_amdgcn_mfma_f32_16x16x32_bf16( \
                    af[m_][kk_], bf[n_][kk_], acc[MH][NH][m_][n_], 0, 0, 0); \
    __builtin_amdgcn_s_setprio(0); \
} while (0)

// 4 phases computing tile in buf RB while staging tile SKT into buf SB.
#define HALF_ITER(RB, SB, SKT) do { \
    LOADA(RB, 0); LOADB(RB, 0); STAGEA(SB, 0, SKT); VMCNT(2); BARR(); MFMA16(0, 0); BARR(); \
    LOADB(RB, 1);               STAGEB(SB, 0, SKT);           BARR(); MFMA16(0, 1); BARR(); \
    LOADA(RB, 1);               STAGEA(SB, 1, SKT);           BARR(); MFMA16(1, 1); BARR(); \
    LOADB(RB, 0);               STAGEB(SB, 1, SKT); VMCNT(4); BARR(); MFMA16(1, 0); BARR(); \
} while (0)

__global__ __launch_bounds__(512, 2) void gemm8_kernel(
    const __bf16* __restrict__ xb, const __bf16* __restrict__ wb,
    const float* __restrict__ bias, float* __restrict__ out) {
    __shared__ __align__(16) unsigned char lds[131072];

    const int tid = threadIdx.x;
    const int lane = tid & 63, wid = tid >> 6;
    const int wr = wid >> 2, wc = wid & 3;
    const int row16 = lane & 15, kq = lane >> 4;

    // XCD-aware swizzle (256 wgs, 256%8==0 -> bijective)
    const int bid = blockIdx.x;
    const int wg = (bid & 7) * 32 + (bid >> 3);
    const int bn = wg & 15, bm = wg >> 4;

    // staging: load j covers rows j*64 + (tid>>3); pre-swizzled source chunk
    const int srow = tid >> 3;
    const int schunk = (tid & 7) ^ (srow & 7);

    f32x4 acc[2][2][4][2] = {};
    bf16x8 af[4][2], bf[2][2];

    // prologue: stage tile 0 fully into buf0; a0,b0 must land before P1.
    STAGEA(0, 0, 0); STAGEB(0, 0, 0); STAGEA(0, 1, 0); STAGEB(0, 1, 0);
    VMCNT(4);
    BARR();

    for (int kt = 0; kt < INF / 64; kt += 2) {
        const int s1 = kt + 1;             // <= 63, always valid
        const int s2 = (kt + 2) & 63;      // wraps on last iter (harmless restage)
        HALF_ITER(0, 1, s1);
        HALF_ITER(1, 0, s2);
    }

    // epilogue: C = acc + bias
#pragma unroll
    for (int nh = 0; nh < 2; ++nh)
#pragma unroll
        for (int n = 0; n < 2; ++n) {
            const int col = bn * 256 + nh * 128 + wc * 32 + n * 16 + row16;
            const float bv = bias[col];
#pragma unroll
            for (int mh = 0; mh < 2; ++mh)
#pragma unroll
                for (int m = 0; m < 4; ++m) {
                    const int rbase = bm * 256 + mh * 128 + wr * 64 + m * 16 + kq * 4;
#pragma unroll
                    for (int j = 0; j < 4; ++j)
                        out[(size_t)(rbase + j) * OUTF + col] = acc[mh][nh][m][n][j] + bv;
                }
        }
}

// ---------------- fallback (no workspace): fused 128^2 kernel ----------------
__global__ __launch_bounds__(256, 2) void gemm_fb_kernel(
    const float* __restrict__ x, const int* __restrict__ wq,
    const float* __restrict__ wn, const float* __restrict__ bias,
    float* __restrict__ out) {
    __shared__ __align__(16) unsigned char lAraw[128 * 128];
    __shared__ __align__(16) unsigned char lBraw[128 * 128];

    const int tid = threadIdx.x;
    const int lane = tid & 63, wid = tid >> 6;
    const int wr = wid >> 1, wc = wid & 1;
    const int bn = blockIdx.x, bm = blockIdx.y;
    const int row16 = lane & 15, kq = lane >> 4;

    f32x4 acc[4][4] = {};

    int aoff[4], boff[4];
#pragma unroll
    for (int m = 0; m < 4; ++m) {
        int r = wr * 64 + m * 16 + row16;
        aoff[m] = r * 128 + ((kq * 16) ^ ((r & 7) << 4));
    }
#pragma unroll
    for (int n = 0; n < 4; ++n) {
        int r = wc * 64 + n * 16 + row16;
        boff[n] = r * 128 + ((kq * 16) ^ ((r & 7) << 4));
    }

    for (int kt = 0; kt < INF / 64; ++kt) {
        __syncthreads();
#pragma unroll
        for (int it = 0; it < 4; ++it) {
            int row = it * 32 + (tid >> 3), c = tid & 7;
            const f32x4* xp = (const f32x4*)(x + (size_t)(bm * 128 + row) * INF + kt * 64 + c * 8);
            f32x4 a0 = xp[0], a1 = xp[1];
            bf16x8 v = { (__bf16)a0[0], (__bf16)a0[1], (__bf16)a0[2], (__bf16)a0[3],
                         (__bf16)a1[0], (__bf16)a1[1], (__bf16)a1[2], (__bf16)a1[3] };
            *(bf16x8*)(lAraw + row * 128 + ((c * 16) ^ ((row & 7) << 4))) = v;
        }
        {
            int row = tid >> 1, gi = tid & 1;
            int gid = (bn * 128 + row) * (INF / GS) + kt * 2 + gi;
            uint64_t lo, hi;
            load_group_bits(wq, gid, lo, hi);
            float nrm = wn[gid];
            float c2 = nrm * (2.0f / 7.0f), c1 = -nrm;
            bf16x8 o[4];
#pragma unroll
            for (int j = 0; j < 32; ++j) {
                uint32_t q = (j <= 20) ? (uint32_t)((lo >> (3 * j)) & 7)
                                       : (uint32_t)((hi >> (3 * j - 32)) & 7);
                o[j >> 3][j & 7] = (__bf16)((float)q * c2 + c1);
            }
            unsigned swz = (row & 7) << 4;
#pragma unroll
            for (int c4 = 0; c4 < 4; ++c4)
                *(bf16x8*)(lBraw + row * 128 + ((gi * 64 + c4 * 16) ^ swz)) = o[c4];
        }
        __syncthreads();

#pragma unroll
        for (int kk = 0; kk < 2; ++kk) {
            bf16x8 afr[4], bfr[4];
#pragma unroll
            for (int m = 0; m < 4; ++m)
                afr[m] = *(const bf16x8*)(lAraw + (aoff[m] ^ (kk * 64)));
#pragma unroll
            for (int n = 0; n < 4; ++n)
                bfr[n] = *(const bf16x8*)(lBraw + (boff[n] ^ (kk * 64)));
#pragma unroll
            for (int m = 0; m < 4; ++m)
#pragma unroll
                for (int n = 0; n < 4; ++n)
                    acc[m][n] = __builtin_amdgcn_mfma_f32_16x16x32_bf16(afr[m], bfr[n], acc[m][n], 0, 0, 0);
        }
    }

#pragma unroll
    for (int n = 0; n < 4; ++n) {
        int col = bn * 128 + wc * 64 + n * 16 + row16;
        float bv = bias[col];
#pragma unroll
        for (int m = 0; m < 4; ++m) {
            int rbase = bm * 128 + wr * 64 + m * 16 + kq * 4;
#pragma unroll
            for (int j = 0; j < 4; ++j)
                out[(size_t)(rbase + j) * OUTF + col] = acc[m][n][j] + bv;
        }
    }
}

extern "C" void kernel_launch(void* const* d_in, const int* in_sizes, int n_in,
                              void* d_out, int out_size, void* d_ws, size_t ws_size,
                              hipStream_t stream) {
    const float* x    = (const float*)d_in[0];
    const int*   wq   = (const int*)d_in[1];
    const float* wn   = (const float*)d_in[2];
    const float* bias = (const float*)d_in[3];
    float* out = (float*)d_out;

    const size_t xb_bytes = (size_t)MROWS * INF * 2;  // 32 MB
    const size_t wb_bytes = (size_t)OUTF * INF * 2;   // 32 MB
    if (ws_size >= xb_bytes + wb_bytes) {
        __bf16* xb = (__bf16*)d_ws;
        __bf16* wb = (__bf16*)((char*)d_ws + xb_bytes);
        cvt_x_kernel<<<(MROWS * INF / 8 + 255) / 256, 256, 0, stream>>>(x, xb, MROWS * INF / 8);
        dequant_w_kernel<<<(OUTF * INF / GS) / 256, 256, 0, stream>>>(wq, wn, wb);
        gemm8_kernel<<<(MROWS / 256) * (OUTF / 256), 512, 0, stream>>>(xb, wb, bias, out);
    } else {
        gemm_fb_kernel<<<dim3(OUTF / 128, MROWS / 128), 256, 0, stream>>>(x, wq, wn, bias, out);
    }
}